// Round 1
// 161.738 us; speedup vs baseline: 1.0521x; 1.0521x over previous
//
#include <hip/hip_runtime.h>
#include <math.h>

// FFTChainMatrix, fully fused frequency-domain factorization.
//   prep : build Bf (33 x 128 x 128 combined spectral operator), Dt2 (DFT
//          basis, fragment-major), E2 (iDFT basis, fragment-major).
//   fused: 256 blocks x 512 thr, 16 tokens/block, everything in LDS:
//     A: XF[f][tok][2i+par] = rfft_64(x blocks)        (MFMA, K=64, N=66)
//     B: per f: YF = XF . Bf[f]^T, in place in LDS     (MFMA, M=16,N=128,K=128)
//     C: y = E . YF  gathered across f slices          (MFMA, M=64,N=128,K=96)
// Eliminates the 3x ~35 MB XF global round trips of the 4-kernel version.

typedef unsigned short u16;
typedef unsigned int   u32;
typedef __attribute__((ext_vector_type(8))) short bf16x8;
typedef __attribute__((ext_vector_type(4))) float f32x4;

#define TWO_PI 6.2831853071795864769f

#define SF 2056                          // u16 per f-slice in LDS (2048 + 8 pad)
                                         // SF/2 = 1028 dw == +4 banks per f
#define BF_ELEMS (33u*128u*128u)         // 540672 u16
#define DT_OFF   BF_ELEMS
#define DT_ELEMS (2u*4u*80u*8u)          // 5120  : [kt][q][n(80)][8]
#define E_OFF    (DT_OFF + DT_ELEMS)
#define E_ELEMS  (3u*4u*64u*8u)          // 6144  : [kt][q][t(64)][8]

__device__ __forceinline__ u16 f2bf(float f) {   // RNE fp32 -> bf16
    union { float f; unsigned u; } v; v.f = f;
    unsigned r = v.u + 0x7FFFu + ((v.u >> 16) & 1u);
    return (u16)(r >> 16);
}

// ---- prep: block 0 -> Dt2/E2 tables; blocks 1..1024 -> Bf ------------------
__global__ void prep(const float* __restrict__ p, const float* __restrict__ cw,
                     u16* __restrict__ Bf, u16* __restrict__ Dt, u16* __restrict__ E) {
    const int tid = threadIdx.x;
    if (blockIdx.x == 0) {
        // Dt2[((kt*4+q)*80 + n)*8 + j] = basis(n, k=kt*32+q*8+j), 16B frags
        for (int e = tid; e < (int)DT_ELEMS; e += 256) {
            int j = e & 7, rowid = e >> 3;
            int n = rowid % 80, grp = rowid / 80;          // grp = kt*4+q
            int k = (grp >> 2) * 32 + (grp & 3) * 8 + j;
            float v = 0.f;
            if (n < 66) {
                int f = n >> 1;
                float ang = TWO_PI * (float)((f * k) & 63) * (1.f / 64.f);
                v = (n & 1) ? -sinf(ang) : cosf(ang);
            }
            Dt[e] = f2bf(v);
        }
        // E2[((kt*4+q)*64 + t)*8 + j] = ibasis(t, k=kt*32+q*8+j), zeros for k>=66
        for (int e = tid; e < (int)E_ELEMS; e += 256) {
            int j = e & 7, rowid = e >> 3;
            int t = rowid % 64, grp = rowid / 64;          // grp = kt*4+q
            int k = (grp >> 2) * 32 + (grp & 3) * 8 + j;
            float v = 0.f;
            if (k < 66) {
                int f = k >> 1;
                float wf = (f == 0 || f == 32) ? 1.f : 2.f;
                float ang = TWO_PI * (float)((f * t) & 63) * (1.f / 64.f);
                v = (wf * (1.f / 64.f)) * ((k & 1) ? -sinf(ang) : cosf(ang));
            }
            E[e] = f2bf(v);
        }
        return;
    }
    // Bf: 4 (o,i) pairs per block (unchanged layout: [f][n=2o+par][k=2i+par])
    __shared__ float  ct[4][64];
    __shared__ float2 trig[64];
    const int pr = tid >> 6, ln = tid & 63;
    if (tid < 64) {
        float s, c;
        sincosf(TWO_PI * (float)tid * (1.f / 64.f), &s, &c);
        trig[tid] = make_float2(s, c);
    }
    const int pg = (blockIdx.x - 1) * 4 + pr;     // 0..4095
    const int o = pg >> 6, i = pg & 63;
    {
        const float* base = p + (size_t)o * 4096 + i * 64 + ln;
        ct[pr][ln] = cw[0] * base[0]      + cw[1] * base[262144]
                   + cw[2] * base[524288] + cw[3] * base[786432];
    }
    __syncthreads();
    if (ln < 33) {        // f = ln
        float cr = 0.f, ci = 0.f;
        for (int u = 0; u < 64; ++u) {
            float2 sc = trig[(ln * u) & 63];
            cr += ct[pr][u] * sc.y; ci -= ct[pr][u] * sc.x;
        }
        u16* b = Bf + (size_t)ln * 16384 + (2 * o) * 128 + 2 * i;
        b[0]   = f2bf(cr);  b[1]   = f2bf(-ci);
        b[128] = f2bf(ci);  b[129] = f2bf(cr);
    }
}

// ---- fused: DFT -> per-f GEMM -> iDFT, one block = 16 tokens ---------------
__global__ __launch_bounds__(512) void fused(const float* __restrict__ x,
                                             const u16* __restrict__ Dt,
                                             const u16* __restrict__ Bf,
                                             const u16* __restrict__ E2,
                                             float* __restrict__ y) {
    __shared__ u16 sm[33 * SF];          // 135,696 B
    const int tid = threadIdx.x, lane = tid & 63, wave = tid >> 6;
    const int lm = lane & 15, q = lane >> 4, kq8 = q * 8, r0 = q * 4;
    const float* xb = x + (size_t)blockIdx.x * (16u * 4096u);

    // -------- phase A: DFT, XF[f][tok][(2i+par)^((tok&7)<<3)] --------------
#pragma unroll
    for (int pass = 0; pass < 2; ++pass) {
        f32x4 acc[4][5];
#pragma unroll
        for (int mi = 0; mi < 4; ++mi)
#pragma unroll
            for (int ni = 0; ni < 5; ++ni) acc[mi][ni] = (f32x4){0.f,0.f,0.f,0.f};
#pragma unroll
        for (int kt = 0; kt < 2; ++kt) {
            bf16x8 bfr[5];
#pragma unroll
            for (int ni = 0; ni < 5; ++ni)      // Dt2 is L2-hot, 16B frags
                bfr[ni] = *(const bf16x8*)&Dt[((kt*4 + q)*80 + ni*16 + lm)*8];
#pragma unroll
            for (int mi = 0; mi < 4; ++mi) {
                const int row = wave*128 + pass*64 + mi*16 + lm;  // (tok,i)
                const float* rp = xb + row*64 + kt*32 + kq8;
                float4 p0 = *(const float4*)rp;
                float4 p1 = *(const float4*)(rp + 4);
                union { u16 u[8]; bf16x8 v; } pk;
                pk.u[0]=f2bf(p0.x); pk.u[1]=f2bf(p0.y);
                pk.u[2]=f2bf(p0.z); pk.u[3]=f2bf(p0.w);
                pk.u[4]=f2bf(p1.x); pk.u[5]=f2bf(p1.y);
                pk.u[6]=f2bf(p1.z); pk.u[7]=f2bf(p1.w);
#pragma unroll
                for (int ni = 0; ni < 5; ++ni)
                    acc[mi][ni] = __builtin_amdgcn_mfma_f32_16x16x32_bf16(
                        pk.v, bfr[ni], acc[mi][ni], 0, 0, 0);
            }
        }
        // scatter C into XF slices (bf16), XOR row-swizzle
#pragma unroll
        for (int mi = 0; mi < 4; ++mi)
#pragma unroll
            for (int ni = 0; ni < 5; ++ni) {
                const int col = ni*16 + lm;
                if (col < 66) {
                    const int f = col >> 1, par = col & 1;
                    const int mb = wave*128 + pass*64 + mi*16 + r0;
                    f32x4 v = acc[mi][ni];
#pragma unroll
                    for (int r = 0; r < 4; ++r) {
                        int m = mb + r, tok = m >> 6, ii = m & 63;
                        sm[f*SF + tok*128 + (((ii<<1)|par) ^ ((tok&7)<<3))] = f2bf(v[r]);
                    }
                }
            }
    }
    __syncthreads();

    // -------- phase B: per f, YF = XF . Bf[f]^T, in place (f per wave) -----
    for (int f = wave; f < 33; f += 8) {
        u16* sl = &sm[f * SF];
        const u16* Bff = Bf + (size_t)f * 16384;
        bf16x8 af[4];                       // full A (M=16) in regs first
#pragma unroll
        for (int ks = 0; ks < 4; ++ks)
            af[ks] = *(const bf16x8*)&sl[lm*128 + ((ks*32 + kq8) ^ ((lm&7)<<3))];
#pragma unroll
        for (int nt = 0; nt < 8; ++nt) {
            f32x4 c = (f32x4){0.f,0.f,0.f,0.f};
#pragma unroll
            for (int ks = 0; ks < 4; ++ks) {  // Bf fragments straight from L2
                bf16x8 bq = *(const bf16x8*)&Bff[(nt*16 + lm)*128 + ks*32 + kq8];
                c = __builtin_amdgcn_mfma_f32_16x16x32_bf16(af[ks], bq, c, 0, 0, 0);
            }
#pragma unroll
            for (int r = 0; r < 4; ++r) {     // write-back: cols nt*16+lm
                int tok = r0 + r;
                sl[tok*128 + ((nt*16 + lm) ^ ((tok&7)<<3))] = f2bf(c[r]);
            }
        }
    }
    __syncthreads();

    // -------- phase C: y = E . YF (A=E so stores are float4 over t) --------
    bf16x8 ef[3][4];
#pragma unroll
    for (int kt = 0; kt < 3; ++kt)
#pragma unroll
        for (int mt = 0; mt < 4; ++mt)        // E2 is L1-resident (12 KB)
            ef[kt][mt] = *(const bf16x8*)&E2[((kt*4 + q)*64 + mt*16 + lm)*8];
#pragma unroll
    for (int nt = 0; nt < 8; ++nt) {          // 128 (tok,o) rows per wave
        const int tokL = wave*2 + (nt >> 2);
        const int o = (nt & 3)*16 + lm;
        const int cb = tokL*128 + ((2*o) ^ ((tokL&7)<<3));
        f32x4 acc[4];
#pragma unroll
        for (int mt = 0; mt < 4; ++mt) acc[mt] = (f32x4){0.f,0.f,0.f,0.f};
#pragma unroll
        for (int kt = 0; kt < 3; ++kt) {
            union { u32 w[4]; bf16x8 v; } bq;  // (re,im) pairs across f slices
#pragma unroll
            for (int j = 0; j < 4; ++j) {
                int f = kt*16 + q*4 + j;
                u32 vv = 0u;
                if (f < 33) vv = *(const u32*)&sm[f*SF + cb];
                bq.w[j] = vv;
            }
#pragma unroll
            for (int mt = 0; mt < 4; ++mt)
                acc[mt] = __builtin_amdgcn_mfma_f32_16x16x32_bf16(
                    ef[kt][mt], bq.v, acc[mt], 0, 0, 0);
        }
        float* yb = y + ((size_t)(blockIdx.x*16 + tokL))*4096 + o*64;
#pragma unroll
        for (int mt = 0; mt < 4; ++mt) {       // 4 consecutive t per lane
            float4 st = { acc[mt][0], acc[mt][1], acc[mt][2], acc[mt][3] };
            *(float4*)&yb[mt*16 + r0] = st;
        }
    }
}

extern "C" void kernel_launch(void* const* d_in, const int* in_sizes, int n_in,
                              void* d_out, int out_size, void* d_ws, size_t ws_size,
                              hipStream_t stream) {
    const float* x      = (const float*)d_in[0];  // (2,2048,4096) fp32
    const float* params = (const float*)d_in[1];  // (4,64,64,64)  fp32
    const float* cw     = (const float*)d_in[2];  // (4,)          fp32
    float* out = (float*)d_out;

    u16* Bf = (u16*)d_ws;
    u16* Dt = Bf + DT_OFF;
    u16* Eg = Bf + E_OFF;

    prep<<<1025, 256, 0, stream>>>(params, cw, Bf, Dt, Eg);
    fused<<<256, 512, 0, stream>>>(x, Dt, Bf, Eg, out);
}

// Round 2
// 161.548 us; speedup vs baseline: 1.0534x; 1.0012x over previous
//
#include <hip/hip_runtime.h>
#include <math.h>

// FFTChainMatrix, fully fused frequency-domain factorization.
//   prep : build Bf (33 x 128 x 128 combined spectral operator), Dt2 (DFT
//          basis, fragment-major), E2 (iDFT basis, fragment-major).
//   fused: 256 blocks x 1024 thr (16 waves), 16 tokens/block, all in LDS:
//     A: XF[f][tok][2i+par] = rfft_64(x blocks)        (MFMA, K=64, N=66)
//     B: per f: YF = XF . Bf[f]^T, in place in LDS     (MFMA, M=16,N=128,K=128)
//     C: y = E . YF  gathered across f slices          (MFMA, M=64,N=128,K=96)
// v2: 512->1024 threads per block. LDS (136 KB) caps us at 1 block/CU; with
// 512 thr that was 2 waves/SIMD (Occupancy 17.8%, MfmaUtil 5.8%, all pipes
// idle => latency-bound). 16 waves doubles waves/SIMD to 4 without adding
// any Bf L2 traffic (wave w owns token w; phase-B slice still 1-wave-owned).

typedef unsigned short u16;
typedef unsigned int   u32;
typedef __attribute__((ext_vector_type(8))) short bf16x8;
typedef __attribute__((ext_vector_type(4))) float f32x4;

#define TWO_PI 6.2831853071795864769f

#define SF 2056                          // u16 per f-slice in LDS (2048 + 8 pad)
                                         // SF/2 = 1028 dw == +4 banks per f
#define BF_ELEMS (33u*128u*128u)         // 540672 u16
#define DT_OFF   BF_ELEMS
#define DT_ELEMS (2u*4u*80u*8u)          // 5120  : [kt][q][n(80)][8]
#define E_OFF    (DT_OFF + DT_ELEMS)
#define E_ELEMS  (3u*4u*64u*8u)          // 6144  : [kt][q][t(64)][8]

__device__ __forceinline__ u16 f2bf(float f) {   // RNE fp32 -> bf16
    union { float f; unsigned u; } v; v.f = f;
    unsigned r = v.u + 0x7FFFu + ((v.u >> 16) & 1u);
    return (u16)(r >> 16);
}

// ---- prep: block 0 -> Dt2/E2 tables; blocks 1..1024 -> Bf ------------------
__global__ void prep(const float* __restrict__ p, const float* __restrict__ cw,
                     u16* __restrict__ Bf, u16* __restrict__ Dt, u16* __restrict__ E) {
    const int tid = threadIdx.x;
    if (blockIdx.x == 0) {
        // Dt2[((kt*4+q)*80 + n)*8 + j] = basis(n, k=kt*32+q*8+j), 16B frags
        for (int e = tid; e < (int)DT_ELEMS; e += 256) {
            int j = e & 7, rowid = e >> 3;
            int n = rowid % 80, grp = rowid / 80;          // grp = kt*4+q
            int k = (grp >> 2) * 32 + (grp & 3) * 8 + j;
            float v = 0.f;
            if (n < 66) {
                int f = n >> 1;
                float ang = TWO_PI * (float)((f * k) & 63) * (1.f / 64.f);
                v = (n & 1) ? -sinf(ang) : cosf(ang);
            }
            Dt[e] = f2bf(v);
        }
        // E2[((kt*4+q)*64 + t)*8 + j] = ibasis(t, k=kt*32+q*8+j), zeros for k>=66
        for (int e = tid; e < (int)E_ELEMS; e += 256) {
            int j = e & 7, rowid = e >> 3;
            int t = rowid % 64, grp = rowid / 64;          // grp = kt*4+q
            int k = (grp >> 2) * 32 + (grp & 3) * 8 + j;
            float v = 0.f;
            if (k < 66) {
                int f = k >> 1;
                float wf = (f == 0 || f == 32) ? 1.f : 2.f;
                float ang = TWO_PI * (float)((f * t) & 63) * (1.f / 64.f);
                v = (wf * (1.f / 64.f)) * ((k & 1) ? -sinf(ang) : cosf(ang));
            }
            E[e] = f2bf(v);
        }
        return;
    }
    // Bf: 4 (o,i) pairs per block (layout: [f][n=2o+par][k=2i+par])
    __shared__ float  ct[4][64];
    __shared__ float2 trig[64];
    const int pr = tid >> 6, ln = tid & 63;
    if (tid < 64) {
        float s, c;
        sincosf(TWO_PI * (float)tid * (1.f / 64.f), &s, &c);
        trig[tid] = make_float2(s, c);
    }
    const int pg = (blockIdx.x - 1) * 4 + pr;     // 0..4095
    const int o = pg >> 6, i = pg & 63;
    {
        const float* base = p + (size_t)o * 4096 + i * 64 + ln;
        ct[pr][ln] = cw[0] * base[0]      + cw[1] * base[262144]
                   + cw[2] * base[524288] + cw[3] * base[786432];
    }
    __syncthreads();
    if (ln < 33) {        // f = ln
        float cr = 0.f, ci = 0.f;
        for (int u = 0; u < 64; ++u) {
            float2 sc = trig[(ln * u) & 63];
            cr += ct[pr][u] * sc.y; ci -= ct[pr][u] * sc.x;
        }
        u16* b = Bf + (size_t)ln * 16384 + (2 * o) * 128 + 2 * i;
        b[0]   = f2bf(cr);  b[1]   = f2bf(-ci);
        b[128] = f2bf(ci);  b[129] = f2bf(cr);
    }
}

// ---- fused: DFT -> per-f GEMM -> iDFT, one block = 16 tokens, 16 waves -----
__global__ __launch_bounds__(1024) void fused(const float* __restrict__ x,
                                              const u16* __restrict__ Dt,
                                              const u16* __restrict__ Bf,
                                              const u16* __restrict__ E2,
                                              float* __restrict__ y) {
    __shared__ u16 sm[33 * SF];          // 135,696 B
    const int tid = threadIdx.x, lane = tid & 63, wave = tid >> 6;
    const int lm = lane & 15, q = lane >> 4, kq8 = q * 8, r0 = q * 4;
    const float* xb = x + (size_t)blockIdx.x * (16u * 4096u);

    // -------- phase A: DFT; wave w owns token w (rows w*64 .. w*64+63) -----
    {
        f32x4 acc[4][5];
#pragma unroll
        for (int mi = 0; mi < 4; ++mi)
#pragma unroll
            for (int ni = 0; ni < 5; ++ni) acc[mi][ni] = (f32x4){0.f,0.f,0.f,0.f};
#pragma unroll
        for (int kt = 0; kt < 2; ++kt) {
            bf16x8 bfr[5];
#pragma unroll
            for (int ni = 0; ni < 5; ++ni)      // Dt2 is L2-hot, 16B frags
                bfr[ni] = *(const bf16x8*)&Dt[((kt*4 + q)*80 + ni*16 + lm)*8];
#pragma unroll
            for (int mi = 0; mi < 4; ++mi) {
                const int row = wave*64 + mi*16 + lm;      // (tok=wave, i)
                const float* rp = xb + row*64 + kt*32 + kq8;
                float4 p0 = *(const float4*)rp;
                float4 p1 = *(const float4*)(rp + 4);
                union { u16 u[8]; bf16x8 v; } pk;
                pk.u[0]=f2bf(p0.x); pk.u[1]=f2bf(p0.y);
                pk.u[2]=f2bf(p0.z); pk.u[3]=f2bf(p0.w);
                pk.u[4]=f2bf(p1.x); pk.u[5]=f2bf(p1.y);
                pk.u[6]=f2bf(p1.z); pk.u[7]=f2bf(p1.w);
#pragma unroll
                for (int ni = 0; ni < 5; ++ni)
                    acc[mi][ni] = __builtin_amdgcn_mfma_f32_16x16x32_bf16(
                        pk.v, bfr[ni], acc[mi][ni], 0, 0, 0);
            }
        }
        // scatter C into XF slices (bf16), XOR row-swizzle; tok == wave
        const int sw = (wave & 7) << 3;
#pragma unroll
        for (int mi = 0; mi < 4; ++mi)
#pragma unroll
            for (int ni = 0; ni < 5; ++ni) {
                const int col = ni*16 + lm;
                if (col < 66) {
                    const int f = col >> 1, par = col & 1;
                    f32x4 v = acc[mi][ni];
#pragma unroll
                    for (int r = 0; r < 4; ++r) {
                        int ii = mi*16 + r0 + r;
                        sm[f*SF + wave*128 + (((ii<<1)|par) ^ sw)] = f2bf(v[r]);
                    }
                }
            }
    }
    __syncthreads();

    // -------- phase B: per f, YF = XF . Bf[f]^T, in place (f per wave) -----
    for (int f = wave; f < 33; f += 16) {
        u16* sl = &sm[f * SF];
        const u16* Bff = Bf + (size_t)f * 16384;
        bf16x8 af[4];                       // full A (M=16 tokens) in regs
#pragma unroll
        for (int ks = 0; ks < 4; ++ks)
            af[ks] = *(const bf16x8*)&sl[lm*128 + ((ks*32 + kq8) ^ ((lm&7)<<3))];
#pragma unroll
        for (int nt = 0; nt < 8; ++nt) {
            f32x4 c = (f32x4){0.f,0.f,0.f,0.f};
#pragma unroll
            for (int ks = 0; ks < 4; ++ks) {  // Bf fragments straight from L2
                bf16x8 bq = *(const bf16x8*)&Bff[(nt*16 + lm)*128 + ks*32 + kq8];
                c = __builtin_amdgcn_mfma_f32_16x16x32_bf16(af[ks], bq, c, 0, 0, 0);
            }
#pragma unroll
            for (int r = 0; r < 4; ++r) {     // write-back: cols nt*16+lm
                int tok = r0 + r;
                sl[tok*128 + ((nt*16 + lm) ^ ((tok&7)<<3))] = f2bf(c[r]);
            }
        }
    }
    __syncthreads();

    // -------- phase C: y = E . YF (A=E so stores are float4 over t) --------
    bf16x8 ef[3][4];
#pragma unroll
    for (int kt = 0; kt < 3; ++kt)
#pragma unroll
        for (int mt = 0; mt < 4; ++mt)        // E2 is L1-resident (12 KB)
            ef[kt][mt] = *(const bf16x8*)&E2[((kt*4 + q)*64 + mt*16 + lm)*8];
    const int tokL = wave;                    // one token per wave
    const int swc = (tokL & 7) << 3;
#pragma unroll
    for (int nt = 0; nt < 4; ++nt) {
        const int o = nt*16 + lm;
        const int cb = tokL*128 + ((2*o) ^ swc);
        f32x4 acc[4];
#pragma unroll
        for (int mt = 0; mt < 4; ++mt) acc[mt] = (f32x4){0.f,0.f,0.f,0.f};
#pragma unroll
        for (int kt = 0; kt < 3; ++kt) {
            union { u32 w[4]; bf16x8 v; } bq;  // (re,im) pairs across f slices
#pragma unroll
            for (int j = 0; j < 4; ++j) {
                int f = kt*16 + q*4 + j;
                u32 vv = 0u;
                if (f < 33) vv = *(const u32*)&sm[f*SF + cb];
                bq.w[j] = vv;
            }
#pragma unroll
            for (int mt = 0; mt < 4; ++mt)
                acc[mt] = __builtin_amdgcn_mfma_f32_16x16x32_bf16(
                    ef[kt][mt], bq.v, acc[mt], 0, 0, 0);
        }
        float* yb = y + ((size_t)(blockIdx.x*16 + tokL))*4096 + o*64;
#pragma unroll
        for (int mt = 0; mt < 4; ++mt) {       // 4 consecutive t per lane
            float4 st = { acc[mt][0], acc[mt][1], acc[mt][2], acc[mt][3] };
            *(float4*)&yb[mt*16 + r0] = st;
        }
    }
}

extern "C" void kernel_launch(void* const* d_in, const int* in_sizes, int n_in,
                              void* d_out, int out_size, void* d_ws, size_t ws_size,
                              hipStream_t stream) {
    const float* x      = (const float*)d_in[0];  // (2,2048,4096) fp32
    const float* params = (const float*)d_in[1];  // (4,64,64,64)  fp32
    const float* cw     = (const float*)d_in[2];  // (4,)          fp32
    float* out = (float*)d_out;

    u16* Bf = (u16*)d_ws;
    u16* Dt = Bf + DT_OFF;
    u16* Eg = Bf + E_OFF;

    prep<<<1025, 256, 0, stream>>>(params, cw, Bf, Dt, Eg);
    fused<<<256, 1024, 0, stream>>>(x, Dt, Bf, Eg, out);
}